// Round 2
// baseline (842.735 us; speedup 1.0000x reference)
//
#include <hip/hip_runtime.h>

#define NEGV (-10000.0f)

constexpr int B_ = 512;
constexpr int S_ = 1024;
constexpr int NL_ = 49;
constexpr int L_ = 51;   // NL + 2; start = 49, end = 50

__global__ __launch_bounds__(64, 1) void crf_fwd(
    const float* __restrict__ logits,      // (B, S, NL)
    const float* __restrict__ transition,  // (L, L)
    const int*   __restrict__ labels,      // (B, S)
    const int*   __restrict__ lens,        // (B,)
    float*       __restrict__ out)         // (B,)
{
    const int b    = blockIdx.x;
    const int lane = threadIdx.x;
    const int len  = __builtin_amdgcn_readfirstlane(lens[b]);  // wave-uniform

    const float* __restrict__ lg  = logits + (size_t)b * (S_ * NL_);
    const int*   __restrict__ lab = labels + (size_t)b * S_;

    __shared__ __align__(16) float sh[52];

    // ---- per-lane transition row, exponentiated, as float4 quads ----
    // lane i holds E[i][j] = exp(T[i][j]) for j=0..50, 0 for j=51 and lanes>=51.
    float4 E4[13];
    float Tend;
    {
        const bool st = (lane < L_);
        const float* trow = transition + (st ? lane : 0) * L_;
        #pragma unroll
        for (int c = 0; c < 13; ++c) {
            float4 e;
            e.x = (st && 4 * c + 0 < L_) ? __expf(trow[4 * c + 0]) : 0.0f;
            e.y = (st && 4 * c + 1 < L_) ? __expf(trow[4 * c + 1]) : 0.0f;
            e.z = (st && 4 * c + 2 < L_) ? __expf(trow[4 * c + 2]) : 0.0f;
            e.w = (st && 4 * c + 3 < L_) ? __expf(trow[4 * c + 3]) : 0.0f;
            E4[c] = e;
        }
        Tend = st ? transition[(L_ - 1) * L_ + lane] : NEGV;
    }

    // ---- gold score: lane-parallel over time ----
    float g = 0.0f;
    for (int t = lane; t < S_; t += 64) {
        if (t < len) {
            int c = lab[t];
            int p = (t == 0) ? (L_ - 2) : lab[t - 1];
            g += lg[t * NL_ + c] + transition[c * L_ + p];
            if (t == len - 1) g += transition[(L_ - 1) * L_ + c];  // end transition
        }
    }
    #pragma unroll
    for (int o = 32; o >= 1; o >>= 1) g += __shfl_xor(g, o, 64);

    // ---- forward scan ----
    // lanes >= 51: Erow = 0 -> y = 0 -> alpha = -inf -> p = 0 forever (harmless)
    float alpha = (lane == L_ - 2) ? 0.0f : NEGV;  // start state
    float M = 0.0f;                                // group-stale max (drift < ~50 over 4 steps)

    auto loadlg = [&](int t) -> float {
        float v = NEGV;
        if (lane < NL_) v = lg[t * NL_ + lane];
        return v;
    };

    auto substep = [&](float cur) {
        float p = __expf(alpha - M);
        sh[lane] = p;
        __syncthreads();   // single wave: waitcnt + cheap barrier; orders write->reads
        float y0 = 0.f, y1 = 0.f, y2 = 0.f, y3 = 0.f;
        #pragma unroll
        for (int c = 0; c < 13; ++c) {
            float4 q = *(const float4*)(sh + 4 * c);   // broadcast read, conflict-free
            y0 = fmaf(q.x, E4[c].x, y0);
            y1 = fmaf(q.y, E4[c].y, y1);
            y2 = fmaf(q.z, E4[c].z, y2);
            y3 = fmaf(q.w, E4[c].w, y3);
        }
        float y = (y0 + y1) + (y2 + y3);
        alpha = cur + M + __logf(y);   // log(0) = -inf for dead rows: OK
    };

    auto update_M = [&]() {
        float r = alpha;
        r = fmaxf(r, __shfl_xor(r, 32, 64));
        r = fmaxf(r, __shfl_xor(r, 16, 64));
        r = fmaxf(r, __shfl_xor(r,  8, 64));
        r = fmaxf(r, __shfl_xor(r,  4, 64));
        r = fmaxf(r, __shfl_xor(r,  2, 64));
        r = fmaxf(r, __shfl_xor(r,  1, 64));
        M = r;
    };

    float b0 = loadlg(0);
    float b1 = loadlg(min(1, S_ - 1));
    float b2 = loadlg(min(2, S_ - 1));
    float b3 = loadlg(min(3, S_ - 1));

    const int nfull = len >> 2;
    int t = 0;
    for (int gI = 0; gI < nfull; ++gI) {
        int u = t + 4;
        float n0 = loadlg(min(u + 0, S_ - 1));
        float n1 = loadlg(min(u + 1, S_ - 1));
        float n2 = loadlg(min(u + 2, S_ - 1));
        float n3 = loadlg(min(u + 3, S_ - 1));
        substep(b0); substep(b1); substep(b2); substep(b3);
        update_M();                  // once per 4 steps: drift-safe, off critical path
        b0 = n0; b1 = n1; b2 = n2; b3 = n3;
        t = u;
    }
    const int rem = len & 3;
    if (rem > 0) {
        substep(b0);
        if (rem > 1) substep(b1);
        if (rem > 2) substep(b2);
    }

    // ---- norm = LSE_i(alpha_i + T[end, i]) ----
    float x = (lane < L_) ? (alpha + Tend) : NEGV;
    float mx = x;
    #pragma unroll
    for (int o = 32; o >= 1; o >>= 1) mx = fmaxf(mx, __shfl_xor(mx, o, 64));
    float e = __expf(x - mx);
    #pragma unroll
    for (int o = 32; o >= 1; o >>= 1) e += __shfl_xor(e, o, 64);
    float norm = mx + __logf(e);

    if (lane == 0) out[b] = g - norm;
}

extern "C" void kernel_launch(void* const* d_in, const int* in_sizes, int n_in,
                              void* d_out, int out_size, void* d_ws, size_t ws_size,
                              hipStream_t stream) {
    const float* logits     = (const float*)d_in[0];
    const float* transition = (const float*)d_in[1];
    const int*   labels     = (const int*)d_in[2];
    const int*   lens       = (const int*)d_in[3];
    float*       out        = (float*)d_out;
    crf_fwd<<<dim3(B_), dim3(64), 0, stream>>>(logits, transition, labels, lens, out);
}

// Round 4
// 782.819 us; speedup vs baseline: 1.0765x; 1.0765x over previous
//
#include <hip/hip_runtime.h>

#define NEGV (-10000.0f)

constexpr int B_ = 512;
constexpr int S_ = 1024;
constexpr int NL_ = 49;
constexpr int L_ = 51;   // NL + 2; start = 49, end = 50

__global__ __launch_bounds__(64, 1) void crf_fwd(
    const float* __restrict__ logits,      // (B, S, NL)
    const float* __restrict__ transition,  // (L, L)
    const int*   __restrict__ labels,      // (B, S)
    const int*   __restrict__ lens,        // (B,)
    float*       __restrict__ out)         // (B,)
{
    const int b    = blockIdx.x;
    const int lane = threadIdx.x;
    const int len  = __builtin_amdgcn_readfirstlane(lens[b]);  // wave-uniform

    const float* __restrict__ lg  = logits + (size_t)b * (S_ * NL_);
    const int*   __restrict__ lab = labels + (size_t)b * S_;

    // Broadcast buffer for the replicated state q. Single wave per block:
    // DS ops from one wave are processed in order by the LDS pipe, and the
    // compiler preserves store->load order on may-alias LDS accesses, so the
    // write->read sequence needs NO barrier/fence (a barrier would drain
    // vmcnt and kill the global prefetch -- round 2's regression).
    __shared__ __align__(16) float sh[64];

    // ---- per-lane row of E = exp(T): lane i holds E[i][0..51] (col 51 = 0) ----
    float4 E4[13];
    float Tend;
    {
        const bool st = (lane < L_);
        const float* trow = transition + (st ? lane : 0) * L_;
        #pragma unroll
        for (int c = 0; c < 13; ++c) {
            float4 e;
            e.x = (st && 4 * c + 0 < L_) ? __expf(trow[4 * c + 0]) : 0.0f;
            e.y = (st && 4 * c + 1 < L_) ? __expf(trow[4 * c + 1]) : 0.0f;
            e.z = (st && 4 * c + 2 < L_) ? __expf(trow[4 * c + 2]) : 0.0f;
            e.w = (st && 4 * c + 3 < L_) ? __expf(trow[4 * c + 3]) : 0.0f;
            E4[c] = e;
        }
        Tend = st ? transition[(L_ - 1) * L_ + lane] : NEGV;
    }

    // ---- gold score: lane-parallel over time (verified rounds 1-2) ----
    float g = 0.0f;
    for (int t = lane; t < S_; t += 64) {
        if (t < len) {
            int c = lab[t];
            int p = (t == 0) ? (L_ - 2) : lab[t - 1];
            g += lg[t * NL_ + c] + transition[c * L_ + p];
            if (t == len - 1) g += transition[(L_ - 1) * L_ + c];
        }
    }
    #pragma unroll
    for (int o = 32; o >= 1; o >>= 1) g += __shfl_xor(g, o, 64);

    // ---- forward scan in LINEAR space: q'_i = u_i * sum_j E_ij q_j ----
    // alpha_i = s + log(q_i); per-step renorm by q_0 keeps q in fp32 range
    // (live-lane spread bounded by transition-row ratios, ~e^18).
    auto loadraw = [&](int t) -> float {
        return (lane < NL_) ? lg[t * NL_ + lane] : NEGV;
    };

    // step 0 peeled: state is delta at start(=49) -> q_i = exp(lg0_i)*E[i][49]
    float q = __expf(loadraw(0)) * E4[12].y;   // col 49 = quad 12 .y
    sh[lane] = q;
    float s = 0.0f;

    auto substep = [&](float raw) -> float {
        float u = __expf(raw);                 // off critical chain (prefetched raw)
        float4 Q[13];
        #pragma unroll
        for (int c = 0; c < 13; ++c) Q[c] = *(const float4*)(sh + 4 * c);  // broadcast
        // renorm factor: IEEE divide (guarded); exact bookkeeping via s -= log(rc).
        // rc depends only on Q[0] (first LDS load) -> ~40 cyc slack under fma chain.
        float rc = 1.0f / fmaxf(Q[0].x, 1e-35f);
        float y0 = 0.f, y1 = 0.f, y2 = 0.f, y3 = 0.f;
        #pragma unroll
        for (int c = 0; c < 13; ++c) {
            y0 = fmaf(Q[c].x, E4[c].x, y0);
            y1 = fmaf(Q[c].y, E4[c].y, y1);
            y2 = fmaf(Q[c].z, E4[c].z, y2);
            y3 = fmaf(Q[c].w, E4[c].w, y3);
        }
        float y = (y0 + y1) + (y2 + y3);
        q = (u * y) * rc;
        sh[lane] = q;
        return rc;
    };

    const int n    = len - 1;    // remaining steps t = 1 .. len-1
    const int nblk = n >> 2;
    const int rem  = n & 3;

    // 8-deep raw-logit prefetch (2 blocks ahead of consumption)
    float a0 = loadraw(1), a1 = loadraw(2), a2 = loadraw(3), a3 = loadraw(4);
    float d0 = loadraw(5), d1 = loadraw(6), d2 = loadraw(7), d3 = loadraw(8);

    int base = 9;
    for (int i = 0; i < nblk; ++i) {
        float e0 = loadraw(min(base + 0, S_ - 1));
        float e1 = loadraw(min(base + 1, S_ - 1));
        float e2 = loadraw(min(base + 2, S_ - 1));
        float e3 = loadraw(min(base + 3, S_ - 1));
        float r0 = substep(a0);
        float r1 = substep(a1);
        float r2 = substep(a2);
        float r3 = substep(a3);
        s -= __logf(r0) + __logf(r1) + __logf(r2) + __logf(r3);  // off-chain
        a0 = d0; a1 = d1; a2 = d2; a3 = d3;
        d0 = e0; d1 = e1; d2 = e2; d3 = e3;
        base += 4;
    }
    if (rem > 0) { float r = substep(a0); s -= __logf(r); }
    if (rem > 1) { float r = substep(a1); s -= __logf(r); }
    if (rem > 2) { float r = substep(a2); s -= __logf(r); }

    // ---- norm = LSE_i(s + log q_i + T[end,i]) ----
    float x = (lane < L_) ? (s + __logf(q) + Tend) : NEGV;   // log(0) = -inf OK
    float mx = x;
    #pragma unroll
    for (int o = 32; o >= 1; o >>= 1) mx = fmaxf(mx, __shfl_xor(mx, o, 64));
    float e = __expf(x - mx);
    #pragma unroll
    for (int o = 32; o >= 1; o >>= 1) e += __shfl_xor(e, o, 64);
    float norm = mx + __logf(e);

    if (lane == 0) out[b] = g - norm;
}

extern "C" void kernel_launch(void* const* d_in, const int* in_sizes, int n_in,
                              void* d_out, int out_size, void* d_ws, size_t ws_size,
                              hipStream_t stream) {
    const float* logits     = (const float*)d_in[0];
    const float* transition = (const float*)d_in[1];
    const int*   labels     = (const int*)d_in[2];
    const int*   lens       = (const int*)d_in[3];
    float*       out        = (float*)d_out;
    crf_fwd<<<dim3(B_), dim3(64), 0, stream>>>(logits, transition, labels, lens, out);
}

// Round 5
// 777.805 us; speedup vs baseline: 1.0835x; 1.0064x over previous
//
#include <hip/hip_runtime.h>

#define NEGV (-10000.0f)

constexpr int B_ = 512;
constexpr int S_ = 1024;
constexpr int NL_ = 49;
constexpr int L_ = 51;   // NL + 2; start = 49, end = 50

__device__ __forceinline__ float4 erow4(const float* trow, bool st, int c) {
    float4 e;
    e.x = (st && 4 * c + 0 < L_) ? __expf(trow[4 * c + 0]) : 0.0f;
    e.y = (st && 4 * c + 1 < L_) ? __expf(trow[4 * c + 1]) : 0.0f;
    e.z = (st && 4 * c + 2 < L_) ? __expf(trow[4 * c + 2]) : 0.0f;
    e.w = (st && 4 * c + 3 < L_) ? __expf(trow[4 * c + 3]) : 0.0f;
    return e;
}

__global__ __launch_bounds__(64, 1) void crf_fwd(
    const float* __restrict__ logits,      // (B, S, NL)
    const float* __restrict__ transition,  // (L, L)
    const int*   __restrict__ labels,      // (B, S)
    const int*   __restrict__ lens,        // (B,)
    float*       __restrict__ out)         // (B,)
{
    const int b    = blockIdx.x;
    const int lane = threadIdx.x;
    const int len  = __builtin_amdgcn_readfirstlane(lens[b]);  // wave-uniform

    const float* __restrict__ lg  = logits + (size_t)b * (S_ * NL_);
    const int*   __restrict__ lab = labels + (size_t)b * S_;

    // Single wave per block: DS ops from one wave are processed in order by
    // the LDS pipe, so write->broadcast-read needs NO barrier (a barrier's
    // vmcnt(0) drain was round 2's regression).
    __shared__ __align__(16) float sh[64];

    // ---- E = exp(T), row i in lane i, as 13 NAMED float4 (no arrays!) ----
    // R1/R2/R4 post-mortem: local arrays were never SROA-promoted (VGPR_Count
    // 40-60 < the 52 floats E needs) -> E lived in scratch and the inner
    // product serialized on scratch-load latency (~1500 cyc/step).
    const bool st = (lane < L_);
    const float* trow = transition + (st ? lane : 0) * L_;
    const float4 e0  = erow4(trow, st, 0),  e1  = erow4(trow, st, 1);
    const float4 e2  = erow4(trow, st, 2),  e3  = erow4(trow, st, 3);
    const float4 e4  = erow4(trow, st, 4),  e5  = erow4(trow, st, 5);
    const float4 e6  = erow4(trow, st, 6),  e7  = erow4(trow, st, 7);
    const float4 e8  = erow4(trow, st, 8),  e9  = erow4(trow, st, 9);
    const float4 e10 = erow4(trow, st, 10), e11 = erow4(trow, st, 11);
    const float4 e12 = erow4(trow, st, 12);
    const float Tend = st ? transition[(L_ - 1) * L_ + lane] : NEGV;

    // ---- gold score: lane-parallel over time (verified rounds 1-4) ----
    float g = 0.0f;
    for (int t = lane; t < S_; t += 64) {
        if (t < len) {
            int c = lab[t];
            int p = (t == 0) ? (L_ - 2) : lab[t - 1];
            g += lg[t * NL_ + c] + transition[c * L_ + p];
            if (t == len - 1) g += transition[(L_ - 1) * L_ + c];
        }
    }
    #pragma unroll
    for (int o = 32; o >= 1; o >>= 1) g += __shfl_xor(g, o, 64);

    // ---- forward scan in LINEAR space: q'_i = u_i * sum_j E_ij q_j ----
    // alpha_i = sacc + log(q_i); per-step renorm by q_0 (exact bookkeeping
    // via sacc -= log(rc)); algorithm identical to round 4 (absmax was 0.0).
#define LOADRAW(t) ((lane < NL_) ? lg[(t) * NL_ + lane] : NEGV)
#define SH4(c) (*(const float4*)(sh + 4 * (c)))

    // step 0 peeled: delta at start(=49) -> q_i = exp(lg0_i) * E[i][49]
    float q = __expf(LOADRAW(0)) * e12.y;   // col 49 = quad 12 .y
    sh[lane] = q;
    float sacc = 0.0f;

#define SUBSTEP(RAW) do {                                                     \
    float4 Q0 = SH4(0);                                                       \
    float rc_ = 1.0f / fmaxf(Q0.x, 1e-35f);      /* off-chain after Q0 */     \
    float w_  = __expf(RAW) * rc_;               /* off-chain (prefetched) */ \
    float4 Q1 = SH4(1),  Q2 = SH4(2),  Q3 = SH4(3),  Q4 = SH4(4);             \
    float4 Q5 = SH4(5),  Q6 = SH4(6),  Q7 = SH4(7),  Q8 = SH4(8);             \
    float4 Q9 = SH4(9),  Q10 = SH4(10), Q11 = SH4(11), Q12 = SH4(12);         \
    float ya0 = Q0.x * e0.x,  ya1 = Q0.y * e0.y;                              \
    float ya2 = Q0.z * e0.z,  ya3 = Q0.w * e0.w;                              \
    float yb0 = Q1.x * e1.x,  yb1 = Q1.y * e1.y;                              \
    float yb2 = Q1.z * e1.z,  yb3 = Q1.w * e1.w;                              \
    ya0 = fmaf(Q2.x,  e2.x,  ya0); ya1 = fmaf(Q2.y,  e2.y,  ya1);             \
    ya2 = fmaf(Q2.z,  e2.z,  ya2); ya3 = fmaf(Q2.w,  e2.w,  ya3);             \
    yb0 = fmaf(Q3.x,  e3.x,  yb0); yb1 = fmaf(Q3.y,  e3.y,  yb1);             \
    yb2 = fmaf(Q3.z,  e3.z,  yb2); yb3 = fmaf(Q3.w,  e3.w,  yb3);             \
    ya0 = fmaf(Q4.x,  e4.x,  ya0); ya1 = fmaf(Q4.y,  e4.y,  ya1);             \
    ya2 = fmaf(Q4.z,  e4.z,  ya2); ya3 = fmaf(Q4.w,  e4.w,  ya3);             \
    yb0 = fmaf(Q5.x,  e5.x,  yb0); yb1 = fmaf(Q5.y,  e5.y,  yb1);             \
    yb2 = fmaf(Q5.z,  e5.z,  yb2); yb3 = fmaf(Q5.w,  e5.w,  yb3);             \
    ya0 = fmaf(Q6.x,  e6.x,  ya0); ya1 = fmaf(Q6.y,  e6.y,  ya1);             \
    ya2 = fmaf(Q6.z,  e6.z,  ya2); ya3 = fmaf(Q6.w,  e6.w,  ya3);             \
    yb0 = fmaf(Q7.x,  e7.x,  yb0); yb1 = fmaf(Q7.y,  e7.y,  yb1);             \
    yb2 = fmaf(Q7.z,  e7.z,  yb2); yb3 = fmaf(Q7.w,  e7.w,  yb3);             \
    ya0 = fmaf(Q8.x,  e8.x,  ya0); ya1 = fmaf(Q8.y,  e8.y,  ya1);             \
    ya2 = fmaf(Q8.z,  e8.z,  ya2); ya3 = fmaf(Q8.w,  e8.w,  ya3);             \
    yb0 = fmaf(Q9.x,  e9.x,  yb0); yb1 = fmaf(Q9.y,  e9.y,  yb1);             \
    yb2 = fmaf(Q9.z,  e9.z,  yb2); yb3 = fmaf(Q9.w,  e9.w,  yb3);             \
    ya0 = fmaf(Q10.x, e10.x, ya0); ya1 = fmaf(Q10.y, e10.y, ya1);             \
    ya2 = fmaf(Q10.z, e10.z, ya2); ya3 = fmaf(Q10.w, e10.w, ya3);             \
    yb0 = fmaf(Q11.x, e11.x, yb0); yb1 = fmaf(Q11.y, e11.y, yb1);             \
    yb2 = fmaf(Q11.z, e11.z, yb2); yb3 = fmaf(Q11.w, e11.w, yb3);             \
    ya0 = fmaf(Q12.x, e12.x, ya0); ya1 = fmaf(Q12.y, e12.y, ya1);             \
    ya2 = fmaf(Q12.z, e12.z, ya2); ya3 = fmaf(Q12.w, e12.w, ya3);             \
    float y_ = ((ya0 + yb0) + (ya1 + yb1)) + ((ya2 + yb2) + (ya3 + yb3));     \
    q = w_ * y_;                                                              \
    sh[lane] = q;                                                             \
    sacc -= __logf(rc_);                         /* off-chain */              \
} while (0)

    const int n    = len - 1;    // steps t = 1 .. len-1
    const int nblk = n >> 2;
    const int rem  = n & 3;

    // 8-deep raw-logit prefetch (2 groups ahead of consumption)
    float p0 = LOADRAW(min(1, S_ - 1)), p1 = LOADRAW(min(2, S_ - 1));
    float p2 = LOADRAW(min(3, S_ - 1)), p3 = LOADRAW(min(4, S_ - 1));
    float r0 = LOADRAW(min(5, S_ - 1)), r1 = LOADRAW(min(6, S_ - 1));
    float r2 = LOADRAW(min(7, S_ - 1)), r3 = LOADRAW(min(8, S_ - 1));

    int base = 9;
    for (int i = 0; i < nblk; ++i) {
        float n0 = LOADRAW(min(base + 0, S_ - 1));
        float n1 = LOADRAW(min(base + 1, S_ - 1));
        float n2 = LOADRAW(min(base + 2, S_ - 1));
        float n3 = LOADRAW(min(base + 3, S_ - 1));
        SUBSTEP(p0);
        SUBSTEP(p1);
        SUBSTEP(p2);
        SUBSTEP(p3);
        p0 = r0; p1 = r1; p2 = r2; p3 = r3;
        r0 = n0; r1 = n1; r2 = n2; r3 = n3;
        base += 4;
    }
    if (rem > 0) SUBSTEP(p0);
    if (rem > 1) SUBSTEP(p1);
    if (rem > 2) SUBSTEP(p2);

    // ---- norm = LSE_i(sacc + log q_i + T[end,i]) ----
    float x = (lane < L_) ? (sacc + __logf(q) + Tend) : NEGV;  // log(0)=-inf OK
    float mx = x;
    #pragma unroll
    for (int o = 32; o >= 1; o >>= 1) mx = fmaxf(mx, __shfl_xor(mx, o, 64));
    float ex = __expf(x - mx);
    #pragma unroll
    for (int o = 32; o >= 1; o >>= 1) ex += __shfl_xor(ex, o, 64);
    float norm = mx + __logf(ex);

    if (lane == 0) out[b] = g - norm;
}

extern "C" void kernel_launch(void* const* d_in, const int* in_sizes, int n_in,
                              void* d_out, int out_size, void* d_ws, size_t ws_size,
                              hipStream_t stream) {
    const float* logits     = (const float*)d_in[0];
    const float* transition = (const float*)d_in[1];
    const int*   labels     = (const int*)d_in[2];
    const int*   lens       = (const int*)d_in[3];
    float*       out        = (float*)d_out;
    crf_fwd<<<dim3(B_), dim3(64), 0, stream>>>(logits, transition, labels, lens, out);
}